// Round 2
// 1073.815 us; speedup vs baseline: 1.1025x; 1.1025x over previous
//
#include <hip/hip_runtime.h>

// SparseEdgeUpdateLayer: out = relu(LN(concat(n_i,n_j,e) @ W1 + b1)) @ W2 + b2
// E=800000, IN=384, OUT=128, fp32 in/out, bf16 MFMA internally.
//
// R1: occupancy attack. BM 64->32 halves the GEMM1 accumulator (96->48 f32/lane,
// unified VGPR/AGPR file) and LDS (52->26 KB), so 3 blocks/CU fit instead of 2
// (__launch_bounds__(256,3)). Streaming edge_feats loads + out stores are
// non-temporal to keep the 25.6 MB node_feats table resident in L3.
// R1b: nontemporal builtins need clang ext_vector types, not HIP float4.

#define E_TOTAL   800000
#define IN_DIM    384
#define NODE_DIM  128
#define OUT_DIM   128
#define KBLK      12      // 384/32 k-blocks
#define NT1       24      // 384/16 n-tiles, gemm1
#define NT2       8       // 128/16 n-tiles, gemm2
#define BM        32      // edges per block
#define MT        2       // m-tiles per block (32/16)
#define NQ1       6       // n-tiles per wave, gemm1 (24/4)
#define NQ2       2       // n-tiles per wave, gemm2 (8/4)
#define ROWP      392     // LDS row stride in bf16 elems (384 + 8 pad)

typedef __bf16 bf16x8 __attribute__((ext_vector_type(8)));
typedef __bf16 bf16x4 __attribute__((ext_vector_type(4)));
typedef float  f32x4  __attribute__((ext_vector_type(4)));

// ---- pack W1 [384x384] and W2 [384x128] into MFMA B-fragment order ----
// B-frag (16x16x32): lane holds B[k = kb*32 + (lane>>4)*8 + j][n = nt*16 + (lane&15)], j=0..7
// packed: Wp[((kb*NT + nt)*64 + lane)*8 + j]
__global__ __launch_bounds__(256) void prep_pack(
    const float* __restrict__ W1, const float* __restrict__ W2,
    __bf16* __restrict__ W1p, __bf16* __restrict__ W2p)
{
    int t = blockIdx.x * 256 + threadIdx.x;
    if (t < KBLK * NT1 * 64) {
        int kb   = t / (NT1 * 64);
        int nt   = (t / 64) % NT1;
        int lane = t & 63;
        int col  = nt * 16 + (lane & 15);
        int k0   = kb * 32 + (lane >> 4) * 8;
        #pragma unroll
        for (int j = 0; j < 8; ++j)
            W1p[(size_t)t * 8 + j] = (__bf16)W1[(size_t)(k0 + j) * IN_DIM + col];
    } else if (t < KBLK * NT1 * 64 + KBLK * NT2 * 64) {
        int t2   = t - KBLK * NT1 * 64;
        int kb   = t2 / (NT2 * 64);
        int nt   = (t2 / 64) % NT2;
        int lane = t2 & 63;
        int col  = nt * 16 + (lane & 15);
        int k0   = kb * 32 + (lane >> 4) * 8;
        #pragma unroll
        for (int j = 0; j < 8; ++j)
            W2p[(size_t)t2 * 8 + j] = (__bf16)W2[(size_t)(k0 + j) * OUT_DIM + col];
    }
}

__global__ __launch_bounds__(256, 3) void fused_edge_update(
    const float* __restrict__ node_feats, const float* __restrict__ edge_feats,
    const int*   __restrict__ ei,
    const float* __restrict__ b1, const float* __restrict__ gamma,
    const float* __restrict__ beta, const float* __restrict__ b2,
    const __bf16* __restrict__ W1p, const __bf16* __restrict__ W2p,
    float* __restrict__ out)
{
    __shared__ __bf16 xs[BM * ROWP];      // x tile, then reused for h tile (25088 B)
    __shared__ float  red[BM][4][2];      // per-wave (sum, sumsq) partials (1 KB)

    const int tid   = threadIdx.x;
    const int wave  = tid >> 6;
    const int lane  = tid & 63;
    const int quad  = lane >> 4;
    const int lcol  = lane & 15;
    const int edge0 = blockIdx.x * BM;

    // ---- gather: 8 threads per edge, 12 float4 chunks per edge ----
    {
        int e_local = tid >> 3;
        int u       = tid & 7;
        int edge    = edge0 + e_local;
        const float* pi = node_feats + (size_t)ei[edge] * NODE_DIM;
        const float* pj = node_feats + (size_t)ei[E_TOTAL + edge] * NODE_DIM;
        const float* pe = edge_feats + (size_t)edge * NODE_DIM;
        #pragma unroll
        for (int p = 0; p < 12; ++p) {
            int c = u + p * 8;   // chunk index 0..95 over the 384-elem row
            f32x4 v;
            if (p < 4)       v = *(const f32x4*)(pi + c * 4);
            else if (p < 8)  v = *(const f32x4*)(pj + (c - 32) * 4);
            else             v = __builtin_nontemporal_load((const f32x4*)(pe + (c - 64) * 4));
            bf16x4 h4 = { (__bf16)v.x, (__bf16)v.y, (__bf16)v.z, (__bf16)v.w };
            *(bf16x4*)(&xs[e_local * ROWP + c * 4]) = h4;
        }
    }
    __syncthreads();

    // ---- GEMM1: h = x @ W1, N-split: wave w computes cols [w*96, w*96+96) ----
    f32x4 acc[MT][NQ1];
    #pragma unroll
    for (int m = 0; m < MT; ++m)
        #pragma unroll
        for (int n = 0; n < NQ1; ++n)
            acc[m][n] = (f32x4){0.f, 0.f, 0.f, 0.f};

    const int nq0 = wave * NQ1;
    for (int kb = 0; kb < KBLK; ++kb) {
        bf16x8 af[MT];
        #pragma unroll
        for (int m = 0; m < MT; ++m)
            af[m] = *(const bf16x8*)(&xs[(m * 16 + lcol) * ROWP + kb * 32 + quad * 8]);
        #pragma unroll
        for (int n = 0; n < NQ1; ++n) {
            bf16x8 bf = *(const bf16x8*)(W1p + (size_t)((kb * NT1 + nq0 + n) * 64 + lane) * 8);
            #pragma unroll
            for (int m = 0; m < MT; ++m)
                acc[m][n] = __builtin_amdgcn_mfma_f32_16x16x32_bf16(af[m], bf, acc[m][n], 0, 0, 0);
        }
    }

    // ---- + b1, then per-row stats (this wave's 96 cols) ----
    float b1v[NQ1], gv[NQ1], bev[NQ1];
    #pragma unroll
    for (int n = 0; n < NQ1; ++n) {
        int col = (nq0 + n) * 16 + lcol;
        b1v[n] = b1[col]; gv[n] = gamma[col]; bev[n] = beta[col];
    }
    #pragma unroll
    for (int m = 0; m < MT; ++m)
        #pragma unroll
        for (int n = 0; n < NQ1; ++n)
            #pragma unroll
            for (int r = 0; r < 4; ++r)
                acc[m][n][r] += b1v[n];

    #pragma unroll
    for (int m = 0; m < MT; ++m) {
        #pragma unroll
        for (int r = 0; r < 4; ++r) {
            float s = 0.f, q = 0.f;
            #pragma unroll
            for (int n = 0; n < NQ1; ++n) { float v = acc[m][n][r]; s += v; q += v * v; }
            #pragma unroll
            for (int msk = 1; msk < 16; msk <<= 1) {  // reduce over the 16 lanes of this quad
                s += __shfl_xor(s, msk, 64);
                q += __shfl_xor(q, msk, 64);
            }
            if (lcol == 0) {
                int row = m * 16 + quad * 4 + r;
                red[row][wave][0] = s;
                red[row][wave][1] = q;
            }
        }
    }
    __syncthreads();   // all GEMM1 xs-reads done; red complete

    // ---- finalize LN stats, normalize + relu, write h (bf16) back into xs ----
    float mu[MT][4], rs[MT][4];
    #pragma unroll
    for (int m = 0; m < MT; ++m) {
        #pragma unroll
        for (int r = 0; r < 4; ++r) {
            int row = m * 16 + quad * 4 + r;
            const f32x4 a = *(const f32x4*)(&red[row][0][0]);
            const f32x4 b = *(const f32x4*)(&red[row][2][0]);
            float s = a.x + a.z + b.x + b.z;
            float q = a.y + a.w + b.y + b.w;
            float mean = s * (1.f / IN_DIM);
            float var  = q * (1.f / IN_DIM) - mean * mean;  // == E[(h-mu)^2]
            mu[m][r] = mean;
            rs[m][r] = rsqrtf(var + 1e-5f);
        }
    }
    #pragma unroll
    for (int m = 0; m < MT; ++m)
        #pragma unroll
        for (int r = 0; r < 4; ++r) {
            int row = m * 16 + quad * 4 + r;
            #pragma unroll
            for (int n = 0; n < NQ1; ++n) {
                int col = (nq0 + n) * 16 + lcol;
                float v = (acc[m][n][r] - mu[m][r]) * rs[m][r] * gv[n] + bev[n];
                v = fmaxf(v, 0.f);
                xs[row * ROWP + col] = (__bf16)v;
            }
        }
    __syncthreads();   // h tile complete before GEMM2 reads all rows

    // ---- GEMM2: out = h @ W2 + b2, N-split: wave w computes cols [w*32, w*32+32) ----
    f32x4 acc2[MT][NQ2];
    #pragma unroll
    for (int m = 0; m < MT; ++m)
        #pragma unroll
        for (int n = 0; n < NQ2; ++n)
            acc2[m][n] = (f32x4){0.f, 0.f, 0.f, 0.f};

    const int nq20 = wave * NQ2;
    for (int kb = 0; kb < KBLK; ++kb) {
        bf16x8 af[MT];
        #pragma unroll
        for (int m = 0; m < MT; ++m)
            af[m] = *(const bf16x8*)(&xs[(m * 16 + lcol) * ROWP + kb * 32 + quad * 8]);
        #pragma unroll
        for (int n = 0; n < NQ2; ++n) {
            bf16x8 bf = *(const bf16x8*)(W2p + (size_t)((kb * NT2 + nq20 + n) * 64 + lane) * 8);
            #pragma unroll
            for (int m = 0; m < MT; ++m)
                acc2[m][n] = __builtin_amdgcn_mfma_f32_16x16x32_bf16(af[m], bf, acc2[m][n], 0, 0, 0);
        }
    }

    float b2v[NQ2];
    #pragma unroll
    for (int n = 0; n < NQ2; ++n)
        b2v[n] = b2[(nq20 + n) * 16 + lcol];

    #pragma unroll
    for (int m = 0; m < MT; ++m)
        #pragma unroll
        for (int n = 0; n < NQ2; ++n)
            #pragma unroll
            for (int r = 0; r < 4; ++r) {
                int rowg = edge0 + m * 16 + quad * 4 + r;
                int col  = (nq20 + n) * 16 + lcol;
                __builtin_nontemporal_store(acc2[m][n][r] + b2v[n],
                                            &out[(size_t)rowg * OUT_DIM + col]);
            }
}

extern "C" void kernel_launch(void* const* d_in, const int* in_sizes, int n_in,
                              void* d_out, int out_size, void* d_ws, size_t ws_size,
                              hipStream_t stream) {
    const float* node_feats = (const float*)d_in[0];
    const float* edge_feats = (const float*)d_in[1];
    const int*   edge_index = (const int*)d_in[2];
    const float* W1    = (const float*)d_in[3];
    const float* b1    = (const float*)d_in[4];
    const float* gamma = (const float*)d_in[5];
    const float* beta  = (const float*)d_in[6];
    const float* W2    = (const float*)d_in[7];
    const float* b2    = (const float*)d_in[8];
    float* out = (float*)d_out;

    __bf16* W1p = (__bf16*)d_ws;                       // 12*24*64*8 bf16 = 294912 B
    __bf16* W2p = W1p + (size_t)KBLK * NT1 * 64 * 8;   // 12*8*64*8 bf16  =  98304 B

    prep_pack<<<96, 256, 0, stream>>>(W1, W2, W1p, W2p);
    fused_edge_update<<<E_TOTAL / BM, 256, 0, stream>>>(
        node_feats, edge_feats, edge_index, b1, gamma, beta, b2, W1p, W2p, out);
}